// Round 12
// baseline (86.902 us; speedup 1.0000x reference)
//
#include <hip/hip_runtime.h>
#include <hip/hip_bf16.h>

#define H1 57   // 64-8+1
#define H2 53   // 57-5+1
#define XP 60   // padded x-stride (x slots)
#define SIP 968 // padded sI y-row stride in f16

typedef _Float16 f16;
typedef _Float16 f16x4 __attribute__((ext_vector_type(4)));
typedef _Float16 f16x8 __attribute__((ext_vector_type(8)));
typedef float f32x4 __attribute__((ext_vector_type(4)));
typedef float f32x16 __attribute__((ext_vector_type(16)));

// ---------------- weight repack + gw transpose + feat zero (grid 32) ----------------
// w1f[(tp*64+l)*8+j] = W1[oc=l&15][c=j&3][kh=tp][kw=2*(l>>4)+(j>>2)]  (c==3 -> 0)
// w2f (32x32x16 fragments): w2f[(tap*64+l)*8+j] = W2[oc=l&31][ch=(l>>5)*8+j][tap]
// gwT2[c*256+t] = {gw[(2t)*66+c], gw[(2t+1)*66+c]}
__global__ __launch_bounds__(256) void k_repack(const float* __restrict__ w1,
    const float* __restrict__ w2, const float* __restrict__ gw,
    f16* __restrict__ w1f, f16* __restrict__ w2f,
    float2* __restrict__ gwT2, float* __restrict__ feat)
{
  const int tid = blockIdx.x * 256 + threadIdx.x;
  const int stride = 32 * 256;
  for (int i = tid; i < 8 * 64 * 8; i += stride) {
    int j = i & 7;
    int l = (i >> 3) & 63;
    int tp = i >> 9;
    int c = j & 3;
    int kw = 2 * (l >> 4) + (j >> 2);
    int oc = l & 15;
    float v = (c < 3) ? w1[((oc * 3 + c) * 8 + tp) * 8 + kw] : 0.f;
    w1f[i] = (f16)v;
  }
  for (int i = tid; i < 25 * 64 * 8; i += stride) {
    int j = i & 7;
    int l = (i >> 3) & 63;
    int tap = i >> 9;
    int oc = l & 31;
    int ch = ((l >> 5) << 3) + j;
    w2f[i] = (f16)w2[((oc * 16 + ch) * 5 + tap / 5) * 5 + tap % 5];
  }
  for (int i = tid; i < 66 * 256; i += stride) {
    int t = i & 255;
    int c = i >> 8;
    float2 v;
    v.x = gw[(2 * t) * 66 + c];
    v.y = gw[(2 * t + 1) * 66 + c];
    gwT2[i] = v;
  }
  for (int i = tid; i < 512 * 32; i += stride) feat[i] = 0.f;   // atomicMax identity
}

// ---------------- conv1: MFMA, swapped operands, row-register A reuse --------------
// Per wave: iterate 9 physical rows; load each A-frag once (f16x8), feed
// acc[r=0] with Bf[row] and acc[r=1] with Bf[row-1]. A-reads 64 -> 36.
__global__ __launch_bounds__(256) void k_conv1(const float* __restrict__ in,
    const f16* __restrict__ w1f, const float* __restrict__ b1,
    f16* __restrict__ O1)
{
  __shared__ __align__(16) f16 sIn[15][72][4];   // 8640 B, c4 channels-last
  const int img = blockIdx.x;
  const int y0 = min((int)blockIdx.y * 8, 49);
  const int lane = threadIdx.x & 63;
  const int wv = threadIdx.x >> 6;

  f16x8 Bf[8];
  #pragma unroll
  for (int tp = 0; tp < 8; ++tp)
    Bf[tp] = *(const f16x8*)&w1f[(tp * 64 + lane) * 8];

  for (int i = threadIdx.x; i < 15 * 16; i += 256) {
    int y = i >> 4, xq = i & 15;
    const float* p0 = &in[(((size_t)img * 3 + 0) * 64 + (y0 + y)) * 64 + xq * 4];
    float4 v0 = *(const float4*)p0;
    float4 v1 = *(const float4*)(p0 + 4096);
    float4 v2 = *(const float4*)(p0 + 8192);
    float c0[4] = {v0.x, v0.y, v0.z, v0.w};
    float c1[4] = {v1.x, v1.y, v1.z, v1.w};
    float c2[4] = {v2.x, v2.y, v2.z, v2.w};
    #pragma unroll
    for (int q = 0; q < 4; ++q) {
      f16x4 tt = {(f16)c0[q], (f16)c1[q], (f16)c2[q], (f16)0.f};
      *(f16x4*)&sIn[y][xq * 4 + q][0] = tt;
    }
  }
  for (int i = threadIdx.x; i < 15 * 8; i += 256) {
    int y = i >> 3, xi = i & 7;
    *(f16x4*)&sIn[y][64 + xi][0] = (f16x4){(f16)0.f, (f16)0.f, (f16)0.f, (f16)0.f};
  }
  __syncthreads();

  const int g = lane >> 4;       // 4-oc group (D rows) / A k-part
  const int n16 = lane & 15;     // px within tile (D col)

  const f32x4 biasv = {b1[g * 4 + 0], b1[g * 4 + 1], b1[g * 4 + 2], b1[g * 4 + 3]};
  f32x4 acc[2][4];
  #pragma unroll
  for (int r = 0; r < 2; ++r)
    #pragma unroll
    for (int xt = 0; xt < 4; ++xt)
      acc[r][xt] = biasv;

  // rows 2wv+0 .. 2wv+8; row feeds (r=0, tp=row) and (r=1, tp=row-1).
  // Per-acc tap order remains 0..7 ascending -> bitwise-identical to round 11.
  #pragma unroll
  for (int row = 0; row <= 8; ++row) {
    const int prow = 2 * wv + row;
    f16x8 a[4];
    #pragma unroll
    for (int xt = 0; xt < 4; ++xt)
      a[xt] = *(const f16x8*)&sIn[prow][xt * 16 + n16 + 2 * g][0];  // 16B read
    if (row < 8) {
      #pragma unroll
      for (int xt = 0; xt < 4; ++xt)
        acc[0][xt] = __builtin_amdgcn_mfma_f32_16x16x32_f16(Bf[row], a[xt], acc[0][xt], 0, 0, 0);
    }
    if (row >= 1) {
      #pragma unroll
      for (int xt = 0; xt < 4; ++xt)
        acc[1][xt] = __builtin_amdgcn_mfma_f32_16x16x32_f16(Bf[row - 1], a[xt], acc[1][xt], 0, 0, 0);
    }
  }

  // epilogue: relu + direct 8B store (4 oc at px) into oct-split channels-last O1
  #pragma unroll
  for (int r = 0; r < 2; ++r) {
    const int yy = y0 + 2 * wv + r;
    f16* rowp = &O1[(((size_t)img * H1 + yy) * 2 + (g >> 1)) * XP * 8 + (g & 1) * 4];
    #pragma unroll
    for (int xt = 0; xt < 4; ++xt) {
      const int px = xt * 16 + n16;
      if (px < H1) {
        f16x4 v;
        #pragma unroll
        for (int q = 0; q < 4; ++q) v[q] = (f16)fmaxf(acc[r][xt][q], 0.f);
        *(f16x4*)&rowp[px * 8] = v;
      }
    }
  }
}

// ---------------- conv2: 32x32x16 MFMA, flattened-M, hybrid reg/LDS B (round-11) ----
__global__ __launch_bounds__(256, 4) void k_conv2(const f16* __restrict__ O1,
    const f16* __restrict__ w2f, const float* __restrict__ b2,
    float* __restrict__ feat)
{
  __shared__ __align__(16) f16 sW[16 * 64 * 8];            // 16384 B (taps 9..24)
  __shared__ __align__(16) f16 sI[12 * SIP + 16];          // 23296 B
  __shared__ unsigned smax[32];
  const int img = blockIdx.x;
  const int y0 = min((int)blockIdx.y * 8, 45);
  const int lane = threadIdx.x & 63;
  const int wv = threadIdx.x >> 6;
  if (threadIdx.x < 32) smax[threadIdx.x] = 0u;

  f16x8 Br[9];
  const f16* pBg = &w2f[lane * 8];
  #pragma unroll
  for (int t = 0; t < 9; ++t)
    Br[t] = *(const f16x8*)(pBg + t * 512);

  for (int i = threadIdx.x; i < 16 * 64; i += 256)
    ((float4*)sW)[i] = ((const float4*)w2f)[9 * 64 + i];
  {
    const float4* src = (const float4*)(O1 + (size_t)(img * H1 + y0) * (2 * XP * 8));
    for (int i = threadIdx.x; i < 1440; i += 256) {
      int y = i / 120;
      int rem = i - y * 120;
      ((float4*)&sI[y * SIP])[rem] = src[i];
    }
  }
  __syncthreads();

  const int m32 = lane & 31;
  const int G = lane >> 5;

  const int start = (wv < 2) ? wv * 4 : 8 + (wv - 2) * 3;
  const int cnt = (wv < 2) ? 4 : 3;

  const float bias = b2[m32];
  f32x16 acc[4];
  #pragma unroll
  for (int ti = 0; ti < 4; ++ti)
    #pragma unroll
    for (int q = 0; q < 16; ++q)
      acc[ti][q] = bias;

  const f16* pA[4];
  #pragma unroll
  for (int ti = 0; ti < 4; ++ti) {
    int t = start + ti;
    int p = t * 32 + m32;
    p = min(p, 423);
    int y = (p * 1237) >> 16;
    int x = p - 53 * y;
    pA[ti] = &sI[y * SIP + G * 480 + x * 8];
  }

  #pragma unroll
  for (int tap = 0; tap < 25; ++tap) {
    const int kh = tap / 5, kw = tap % 5;
    const int off = kh * SIP + kw * 8;
    f16x8 Bv = (tap < 9) ? Br[tap] : *(const f16x8*)(&sW[lane * 8] + (tap - 9) * 512);
    #pragma unroll
    for (int ti = 0; ti < 4; ++ti) {
      if (ti < cnt) {
        f16x8 Av = *(const f16x8*)(pA[ti] + off);
        acc[ti] = __builtin_amdgcn_mfma_f32_32x32x16_f16(Av, Bv, acc[ti], 0, 0, 0);
      }
    }
  }

  float m = 0.f;
  #pragma unroll
  for (int ti = 0; ti < 4; ++ti) {
    if (ti < cnt) {
      const int t = start + ti;
      #pragma unroll
      for (int q = 0; q < 16; ++q) {
        if (t == 13 && q >= 4) continue;
        m = fmaxf(m, acc[ti][q]);
      }
    }
  }
  m = fmaxf(m, 0.f);
  m = fmaxf(m, __shfl_xor(m, 32, 64));
  if (lane < 32) atomicMax(&smax[m32], __float_as_uint(m));
  __syncthreads();
  if (threadIdx.x < 32)
    atomicMax((unsigned*)&feat[img * 32 + threadIdx.x], smax[threadIdx.x]);
}

// ---------------- head: adjacency + graph layer + MLP (coalesced GEMV) ----------------
__global__ __launch_bounds__(256) void k_head(const float* __restrict__ diffs,
    const float* __restrict__ feat, const float2* __restrict__ gwT2,
    const float* __restrict__ gb, const float* __restrict__ w4,
    const float* __restrict__ b4, const float* __restrict__ w5,
    const float* __restrict__ b5, float* __restrict__ out)
{
  __shared__ float h66[4][66];
  __shared__ float hout[4][512];
  __shared__ float Am[4][4];
  __shared__ float pd[4][4][2];
  __shared__ float fs[4][32];
  const int b = blockIdx.x;
  const int tid = threadIdx.x;
  if (tid < 128) {
    int i = tid >> 5, c = tid & 31;
    fs[i][c] = feat[(b * 4 + i) * 32 + c];
  }
  if (tid == 0) {
    float lx[4], ly[4];
    #pragma unroll
    for (int a = 0; a < 4; ++a) {
      lx[a] = diffs[(b * 4 + a) * 2];
      ly[a] = diffs[(b * 4 + a) * 2 + 1];
    }
    #pragma unroll
    for (int i = 0; i < 4; ++i) {
      float A[4];
      float rs = 0.f;
      #pragma unroll
      for (int j = 0; j < 4; ++j) {
        float dx = lx[i] - lx[j], dy = ly[i] - ly[j];
        pd[i][j][0] = dx;
        pd[i][j][1] = dy;
        float n = sqrtf(dx * dx + dy * dy);
        A[j] = (n < 1.41421356237309504880f) ? 1.f : 0.f;
        rs += A[j];
      }
      float inv = 1.f / fmaxf(rs, 1e-6f);
      #pragma unroll
      for (int j = 0; j < 4; ++j)
        Am[i][j] = (i == j) ? 0.f : A[j] * inv;
    }
  }
  __syncthreads();
  if (tid < 128) {
    int i = tid >> 5, c = tid & 31;
    h66[i][c] = fs[i][c];
    float s = 0.f;
    #pragma unroll
    for (int j = 0; j < 4; ++j) s += Am[i][j] * fs[j][c];
    h66[i][32 + c] = s;
  } else if (tid < 136) {
    int q = tid - 128;
    int i = q >> 1, d = q & 1;
    float s = 0.f;
    #pragma unroll
    for (int j = 0; j < 4; ++j) s += Am[i][j] * pd[i][j][d];
    h66[i][64 + d] = s;
  }
  __syncthreads();
  {
    const float b0 = gb[2 * tid], b1g = gb[2 * tid + 1];
    float a[4][2];
    #pragma unroll
    for (int i = 0; i < 4; ++i) { a[i][0] = b0; a[i][1] = b1g; }
    #pragma unroll 6
    for (int c = 0; c < 66; ++c) {
      float2 w = gwT2[c * 256 + tid];
      #pragma unroll
      for (int i = 0; i < 4; ++i) {
        float h = h66[i][c];
        a[i][0] = fmaf(h, w.x, a[i][0]);
        a[i][1] = fmaf(h, w.y, a[i][1]);
      }
    }
    #pragma unroll
    for (int i = 0; i < 4; ++i) {
      float2 v;
      v.x = fmaxf(a[i][0], 0.f);
      v.y = fmaxf(a[i][1], 0.f);
      *(float2*)&hout[i][2 * tid] = v;
    }
  }
  __syncthreads();
  if (tid < 192) {
    int gq = tid >> 4, l = tid & 15;
    int i = gq / 3, k = gq % 3;
    const float* wrow = (k < 2) ? &w4[k * 512] : w5;
    float s = 0.f;
    for (int o = l; o < 512; o += 16) s = fmaf(hout[i][o], wrow[o], s);
    #pragma unroll
    for (int d = 8; d >= 1; d >>= 1) s += __shfl_xor(s, d, 16);
    if (l == 0) {
      if (k < 2) out[(b * 4 + i) * 2 + k] = s + b4[k];
      else       out[1024 + b * 4 + i] = s + b5[0];
    }
  }
}

extern "C" void kernel_launch(void* const* d_in, const int* in_sizes, int n_in,
                              void* d_out, int out_size, void* d_ws, size_t ws_size,
                              hipStream_t stream) {
  const float* diffs  = (const float*)d_in[0];
  const float* states = (const float*)d_in[1];
  const float* w1 = (const float*)d_in[2];
  const float* b1 = (const float*)d_in[3];
  const float* w2 = (const float*)d_in[4];
  const float* b2 = (const float*)d_in[5];
  const float* gw = (const float*)d_in[6];
  const float* gb = (const float*)d_in[7];
  const float* w4 = (const float*)d_in[8];
  const float* b4 = (const float*)d_in[9];
  const float* w5 = (const float*)d_in[10];
  const float* b5 = (const float*)d_in[11];
  float* out = (float*)d_out;

  char* base = (char*)d_ws;
  f16*    w1f  = (f16*)base;                    // 8192 B
  f16*    w2f  = (f16*)(base + 8192);           // 25600 B -> ends 33792
  float2* gwT2 = (float2*)(base + 34816);       // 135168 B -> 169984
  float*  feat = (float*)(base + 169984);       // 65536 B -> 235520
  f16*    O1   = (f16*)(base + 235520);         // 512*57*2*60*8 f16 = 56.0 MB

  k_repack<<<32, 256, 0, stream>>>(w1, w2, gw, w1f, w2f, gwT2, feat);
  k_conv1<<<dim3(512, 8), 256, 0, stream>>>(states, w1f, b1, O1);
  k_conv2<<<dim3(512, 7), 256, 0, stream>>>(O1, w2f, b2, feat);
  k_head<<<128, 256, 0, stream>>>(diffs, feat, gwT2, gb, w4, b4, w5, b5, out);
}

// Round 13
// 86.754 us; speedup vs baseline: 1.0017x; 1.0017x over previous
//
#include <hip/hip_runtime.h>
#include <hip/hip_bf16.h>

#define H1 57   // 64-8+1
#define H2 53   // 57-5+1
#define XP 60   // padded x-stride (x slots)
#define SIP 968 // padded sI y-row stride in f16

typedef _Float16 f16;
typedef _Float16 f16x4 __attribute__((ext_vector_type(4)));
typedef _Float16 f16x8 __attribute__((ext_vector_type(8)));
typedef float f32x4 __attribute__((ext_vector_type(4)));
typedef float f32x16 __attribute__((ext_vector_type(16)));

// ---------------- weight repack + gw transpose + feat zero (grid 32) ----------------
// w1f[(tp*64+l)*8+j] = W1[oc=l&15][c=j&3][kh=tp][kw=2*(l>>4)+(j>>2)]  (c==3 -> 0)
// w2f (32x32x16 fragments): w2f[(tap*64+l)*8+j] = W2[oc=l&31][ch=(l>>5)*8+j][tap]
// gwT2[c*256+t] = {gw[(2t)*66+c], gw[(2t+1)*66+c]}
__global__ __launch_bounds__(256) void k_repack(const float* __restrict__ w1,
    const float* __restrict__ w2, const float* __restrict__ gw,
    f16* __restrict__ w1f, f16* __restrict__ w2f,
    float2* __restrict__ gwT2, float* __restrict__ feat)
{
  const int tid = blockIdx.x * 256 + threadIdx.x;
  const int stride = 32 * 256;
  for (int i = tid; i < 8 * 64 * 8; i += stride) {
    int j = i & 7;
    int l = (i >> 3) & 63;
    int tp = i >> 9;
    int c = j & 3;
    int kw = 2 * (l >> 4) + (j >> 2);
    int oc = l & 15;
    float v = (c < 3) ? w1[((oc * 3 + c) * 8 + tp) * 8 + kw] : 0.f;
    w1f[i] = (f16)v;
  }
  for (int i = tid; i < 25 * 64 * 8; i += stride) {
    int j = i & 7;
    int l = (i >> 3) & 63;
    int tap = i >> 9;
    int oc = l & 31;
    int ch = ((l >> 5) << 3) + j;
    w2f[i] = (f16)w2[((oc * 16 + ch) * 5 + tap / 5) * 5 + tap % 5];
  }
  for (int i = tid; i < 66 * 256; i += stride) {
    int t = i & 255;
    int c = i >> 8;
    float2 v;
    v.x = gw[(2 * t) * 66 + c];
    v.y = gw[(2 * t + 1) * 66 + c];
    gwT2[i] = v;
  }
  for (int i = tid; i < 512 * 32; i += stride) feat[i] = 0.f;   // atomicMax identity
}

// ---------------- conv1: MFMA, swapped operands, 16-row strips -----------------------
// grid (512, 4): y0 = min(16*by, 41). Wave owns 4 output rows; physical rows
// 4wv+row (row 0..10) each read ONCE and feed acc[r] with Bf[row-r].
// Halo re-read 23/16 = 1.44x (vs 1.87x at 8-row strips).
__global__ __launch_bounds__(256) void k_conv1(const float* __restrict__ in,
    const f16* __restrict__ w1f, const float* __restrict__ b1,
    f16* __restrict__ O1)
{
  __shared__ __align__(16) f16 sIn[23][72][4];   // 13248 B, c4 channels-last
  const int img = blockIdx.x;
  const int y0 = min((int)blockIdx.y * 16, 41);
  const int lane = threadIdx.x & 63;
  const int wv = threadIdx.x >> 6;

  f16x8 Bf[8];
  #pragma unroll
  for (int tp = 0; tp < 8; ++tp)
    Bf[tp] = *(const f16x8*)&w1f[(tp * 64 + lane) * 8];

  for (int i = threadIdx.x; i < 23 * 16; i += 256) {
    int y = i >> 4, xq = i & 15;
    int yy = min(y0 + y, 63);
    const float* p0 = &in[(((size_t)img * 3 + 0) * 64 + yy) * 64 + xq * 4];
    float4 v0 = *(const float4*)p0;
    float4 v1 = *(const float4*)(p0 + 4096);
    float4 v2 = *(const float4*)(p0 + 8192);
    float c0[4] = {v0.x, v0.y, v0.z, v0.w};
    float c1[4] = {v1.x, v1.y, v1.z, v1.w};
    float c2[4] = {v2.x, v2.y, v2.z, v2.w};
    #pragma unroll
    for (int q = 0; q < 4; ++q) {
      f16x4 tt = {(f16)c0[q], (f16)c1[q], (f16)c2[q], (f16)0.f};
      *(f16x4*)&sIn[y][xq * 4 + q][0] = tt;
    }
  }
  for (int i = threadIdx.x; i < 23 * 8; i += 256) {
    int y = i >> 3, xi = i & 7;
    *(f16x4*)&sIn[y][64 + xi][0] = (f16x4){(f16)0.f, (f16)0.f, (f16)0.f, (f16)0.f};
  }
  __syncthreads();

  const int g = lane >> 4;       // 4-oc group (D rows) / A k-part
  const int n16 = lane & 15;     // px within tile (D col)

  const f32x4 biasv = {b1[g * 4 + 0], b1[g * 4 + 1], b1[g * 4 + 2], b1[g * 4 + 3]};
  f32x4 acc[4][4];
  #pragma unroll
  for (int r = 0; r < 4; ++r)
    #pragma unroll
    for (int xt = 0; xt < 4; ++xt)
      acc[r][xt] = biasv;

  // rows 4wv+0 .. 4wv+10; row feeds acc[r] with tp=row-r (0<=tp<=7).
  // Per-acc tap order remains 0..7 ascending -> bitwise-identical results.
  #pragma unroll
  for (int row = 0; row <= 10; ++row) {
    const int prow = 4 * wv + row;
    f16x8 a[4];
    #pragma unroll
    for (int xt = 0; xt < 4; ++xt)
      a[xt] = *(const f16x8*)&sIn[prow][xt * 16 + n16 + 2 * g][0];  // 16B read
    #pragma unroll
    for (int r = 0; r < 4; ++r) {
      const int tp = row - r;
      if (tp >= 0 && tp < 8) {
        #pragma unroll
        for (int xt = 0; xt < 4; ++xt)
          acc[r][xt] = __builtin_amdgcn_mfma_f32_16x16x32_f16(Bf[tp], a[xt], acc[r][xt], 0, 0, 0);
      }
    }
  }

  // epilogue: relu + direct 8B store (4 oc at px) into oct-split channels-last O1
  #pragma unroll
  for (int r = 0; r < 4; ++r) {
    const int yy = y0 + 4 * wv + r;
    f16* rowp = &O1[(((size_t)img * H1 + yy) * 2 + (g >> 1)) * XP * 8 + (g & 1) * 4];
    #pragma unroll
    for (int xt = 0; xt < 4; ++xt) {
      const int px = xt * 16 + n16;
      if (px < H1) {
        f16x4 v;
        #pragma unroll
        for (int q = 0; q < 4; ++q) v[q] = (f16)fmaxf(acc[r][xt][q], 0.f);
        *(f16x4*)&rowp[px * 8] = v;
      }
    }
  }
}

// ---------------- conv2: 32x32x16 MFMA, flattened-M, hybrid reg/LDS B (round-11) ----
__global__ __launch_bounds__(256, 4) void k_conv2(const f16* __restrict__ O1,
    const f16* __restrict__ w2f, const float* __restrict__ b2,
    float* __restrict__ feat)
{
  __shared__ __align__(16) f16 sW[16 * 64 * 8];            // 16384 B (taps 9..24)
  __shared__ __align__(16) f16 sI[12 * SIP + 16];          // 23296 B
  __shared__ unsigned smax[32];
  const int img = blockIdx.x;
  const int y0 = min((int)blockIdx.y * 8, 45);
  const int lane = threadIdx.x & 63;
  const int wv = threadIdx.x >> 6;
  if (threadIdx.x < 32) smax[threadIdx.x] = 0u;

  f16x8 Br[9];
  const f16* pBg = &w2f[lane * 8];
  #pragma unroll
  for (int t = 0; t < 9; ++t)
    Br[t] = *(const f16x8*)(pBg + t * 512);

  for (int i = threadIdx.x; i < 16 * 64; i += 256)
    ((float4*)sW)[i] = ((const float4*)w2f)[9 * 64 + i];
  {
    const float4* src = (const float4*)(O1 + (size_t)(img * H1 + y0) * (2 * XP * 8));
    for (int i = threadIdx.x; i < 1440; i += 256) {
      int y = i / 120;
      int rem = i - y * 120;
      ((float4*)&sI[y * SIP])[rem] = src[i];
    }
  }
  __syncthreads();

  const int m32 = lane & 31;
  const int G = lane >> 5;

  const int start = (wv < 2) ? wv * 4 : 8 + (wv - 2) * 3;
  const int cnt = (wv < 2) ? 4 : 3;

  const float bias = b2[m32];
  f32x16 acc[4];
  #pragma unroll
  for (int ti = 0; ti < 4; ++ti)
    #pragma unroll
    for (int q = 0; q < 16; ++q)
      acc[ti][q] = bias;

  const f16* pA[4];
  #pragma unroll
  for (int ti = 0; ti < 4; ++ti) {
    int t = start + ti;
    int p = t * 32 + m32;
    p = min(p, 423);
    int y = (p * 1237) >> 16;
    int x = p - 53 * y;
    pA[ti] = &sI[y * SIP + G * 480 + x * 8];
  }

  #pragma unroll
  for (int tap = 0; tap < 25; ++tap) {
    const int kh = tap / 5, kw = tap % 5;
    const int off = kh * SIP + kw * 8;
    f16x8 Bv = (tap < 9) ? Br[tap] : *(const f16x8*)(&sW[lane * 8] + (tap - 9) * 512);
    #pragma unroll
    for (int ti = 0; ti < 4; ++ti) {
      if (ti < cnt) {
        f16x8 Av = *(const f16x8*)(pA[ti] + off);
        acc[ti] = __builtin_amdgcn_mfma_f32_32x32x16_f16(Av, Bv, acc[ti], 0, 0, 0);
      }
    }
  }

  float m = 0.f;
  #pragma unroll
  for (int ti = 0; ti < 4; ++ti) {
    if (ti < cnt) {
      const int t = start + ti;
      #pragma unroll
      for (int q = 0; q < 16; ++q) {
        if (t == 13 && q >= 4) continue;
        m = fmaxf(m, acc[ti][q]);
      }
    }
  }
  m = fmaxf(m, 0.f);
  m = fmaxf(m, __shfl_xor(m, 32, 64));
  if (lane < 32) atomicMax(&smax[m32], __float_as_uint(m));
  __syncthreads();
  if (threadIdx.x < 32)
    atomicMax((unsigned*)&feat[img * 32 + threadIdx.x], smax[threadIdx.x]);
}

// ---------------- head: adjacency + graph layer + MLP (coalesced GEMV) ----------------
__global__ __launch_bounds__(256) void k_head(const float* __restrict__ diffs,
    const float* __restrict__ feat, const float2* __restrict__ gwT2,
    const float* __restrict__ gb, const float* __restrict__ w4,
    const float* __restrict__ b4, const float* __restrict__ w5,
    const float* __restrict__ b5, float* __restrict__ out)
{
  __shared__ float h66[4][66];
  __shared__ float hout[4][512];
  __shared__ float Am[4][4];
  __shared__ float pd[4][4][2];
  __shared__ float fs[4][32];
  const int b = blockIdx.x;
  const int tid = threadIdx.x;
  if (tid < 128) {
    int i = tid >> 5, c = tid & 31;
    fs[i][c] = feat[(b * 4 + i) * 32 + c];
  }
  if (tid == 0) {
    float lx[4], ly[4];
    #pragma unroll
    for (int a = 0; a < 4; ++a) {
      lx[a] = diffs[(b * 4 + a) * 2];
      ly[a] = diffs[(b * 4 + a) * 2 + 1];
    }
    #pragma unroll
    for (int i = 0; i < 4; ++i) {
      float A[4];
      float rs = 0.f;
      #pragma unroll
      for (int j = 0; j < 4; ++j) {
        float dx = lx[i] - lx[j], dy = ly[i] - ly[j];
        pd[i][j][0] = dx;
        pd[i][j][1] = dy;
        float n = sqrtf(dx * dx + dy * dy);
        A[j] = (n < 1.41421356237309504880f) ? 1.f : 0.f;
        rs += A[j];
      }
      float inv = 1.f / fmaxf(rs, 1e-6f);
      #pragma unroll
      for (int j = 0; j < 4; ++j)
        Am[i][j] = (i == j) ? 0.f : A[j] * inv;
    }
  }
  __syncthreads();
  if (tid < 128) {
    int i = tid >> 5, c = tid & 31;
    h66[i][c] = fs[i][c];
    float s = 0.f;
    #pragma unroll
    for (int j = 0; j < 4; ++j) s += Am[i][j] * fs[j][c];
    h66[i][32 + c] = s;
  } else if (tid < 136) {
    int q = tid - 128;
    int i = q >> 1, d = q & 1;
    float s = 0.f;
    #pragma unroll
    for (int j = 0; j < 4; ++j) s += Am[i][j] * pd[i][j][d];
    h66[i][64 + d] = s;
  }
  __syncthreads();
  {
    const float b0 = gb[2 * tid], b1g = gb[2 * tid + 1];
    float a[4][2];
    #pragma unroll
    for (int i = 0; i < 4; ++i) { a[i][0] = b0; a[i][1] = b1g; }
    #pragma unroll 6
    for (int c = 0; c < 66; ++c) {
      float2 w = gwT2[c * 256 + tid];
      #pragma unroll
      for (int i = 0; i < 4; ++i) {
        float h = h66[i][c];
        a[i][0] = fmaf(h, w.x, a[i][0]);
        a[i][1] = fmaf(h, w.y, a[i][1]);
      }
    }
    #pragma unroll
    for (int i = 0; i < 4; ++i) {
      float2 v;
      v.x = fmaxf(a[i][0], 0.f);
      v.y = fmaxf(a[i][1], 0.f);
      *(float2*)&hout[i][2 * tid] = v;
    }
  }
  __syncthreads();
  if (tid < 192) {
    int gq = tid >> 4, l = tid & 15;
    int i = gq / 3, k = gq % 3;
    const float* wrow = (k < 2) ? &w4[k * 512] : w5;
    float s = 0.f;
    for (int o = l; o < 512; o += 16) s = fmaf(hout[i][o], wrow[o], s);
    #pragma unroll
    for (int d = 8; d >= 1; d >>= 1) s += __shfl_xor(s, d, 16);
    if (l == 0) {
      if (k < 2) out[(b * 4 + i) * 2 + k] = s + b4[k];
      else       out[1024 + b * 4 + i] = s + b5[0];
    }
  }
}

extern "C" void kernel_launch(void* const* d_in, const int* in_sizes, int n_in,
                              void* d_out, int out_size, void* d_ws, size_t ws_size,
                              hipStream_t stream) {
  const float* diffs  = (const float*)d_in[0];
  const float* states = (const float*)d_in[1];
  const float* w1 = (const float*)d_in[2];
  const float* b1 = (const float*)d_in[3];
  const float* w2 = (const float*)d_in[4];
  const float* b2 = (const float*)d_in[5];
  const float* gw = (const float*)d_in[6];
  const float* gb = (const float*)d_in[7];
  const float* w4 = (const float*)d_in[8];
  const float* b4 = (const float*)d_in[9];
  const float* w5 = (const float*)d_in[10];
  const float* b5 = (const float*)d_in[11];
  float* out = (float*)d_out;

  char* base = (char*)d_ws;
  f16*    w1f  = (f16*)base;                    // 8192 B
  f16*    w2f  = (f16*)(base + 8192);           // 25600 B -> ends 33792
  float2* gwT2 = (float2*)(base + 34816);       // 135168 B -> 169984
  float*  feat = (float*)(base + 169984);       // 65536 B -> 235520
  f16*    O1   = (f16*)(base + 235520);         // 512*57*2*60*8 f16 = 56.0 MB

  k_repack<<<32, 256, 0, stream>>>(w1, w2, gw, w1f, w2f, gwT2, feat);
  k_conv1<<<dim3(512, 4), 256, 0, stream>>>(states, w1f, b1, O1);
  k_conv2<<<dim3(512, 7), 256, 0, stream>>>(O1, w2f, b2, feat);
  k_head<<<128, 256, 0, stream>>>(diffs, feat, gwT2, gb, w4, b4, w5, b5, out);
}